// Round 1
// baseline (1412.324 us; speedup 1.0000x reference)
//
#include <hip/hip_runtime.h>
#include <hip/hip_bf16.h>

// LinearStateSpace: y_t = C x_t + D u_t, x_{t+1} = A x_t + B u_t, rho(A)=0.9.
// Strategy: truncated convolution y_t = D u_t + sum_{d=1..LTRUNC} (C A^{d-1} B) u_{t-d}.
// 0.9^113 ~ 7e-6 -> truncation error ~1e-3 abs, threshold is 0.289.

#define NSTEPS 32768
#define LTRUNC 112               // history length (delay blocks d=1..112)
#define NDBLK  (LTRUNC + 1)      // 113 blocks incl. d=0 (= D)
#define KTOT   (NDBLK * 128)     // 14464 contraction length of the conv GEMM

typedef __attribute__((ext_vector_type(8))) short short8;
typedef __attribute__((ext_vector_type(4))) float f32x4;

// ---------- generic f32 GEMM: C += A(MxK) @ B(KxN), row-major, 64x64 tile,
// ---------- split-K=4 (atomic accumulate; output must be pre-zeroed), batched via z.
__global__ __launch_bounds__(256) void gemm_f32(
    const float* __restrict__ Ag, const float* __restrict__ Bg, float* __restrict__ Cg,
    int K, int lda, int ldb, int ldc, int nsplit, long bsB, long bsC)
{
  const int z = blockIdx.z;
  const int batch = z / nsplit, split = z - batch * nsplit;
  const float* B = Bg + (size_t)batch * bsB;
  float* C = Cg + (size_t)batch * bsC;
  const int kChunk = K / nsplit;
  const int m0 = blockIdx.y << 6, n0 = blockIdx.x << 6;
  const int tid = threadIdx.x;
  __shared__ float As[16][68];   // A-tile transposed [k][m], padded vs bank conflicts
  __shared__ float Bs[16][68];   // B-tile [k][n]
  float acc[4][4] = {};
  const int tx = tid & 15, ty = tid >> 4;
  const int ar = tid >> 2, ac4 = (tid & 3) << 2;
  const int bk = tid >> 4, bc4 = (tid & 15) << 2;
  const float* Aptr = Ag + (size_t)(m0 + ar) * lda + ac4;
  const float* Bptr = B + (size_t)bk * ldb + n0 + bc4;
  const int kend = (split + 1) * kChunk;
  for (int kt = split * kChunk; kt < kend; kt += 16) {
    const float4 av = *reinterpret_cast<const float4*>(Aptr + kt);
    const float4 bv = *reinterpret_cast<const float4*>(Bptr + (size_t)kt * ldb);
    __syncthreads();
    As[ac4 + 0][ar] = av.x;
    As[ac4 + 1][ar] = av.y;
    As[ac4 + 2][ar] = av.z;
    As[ac4 + 3][ar] = av.w;
    *reinterpret_cast<float4*>(&Bs[bk][bc4]) = bv;
    __syncthreads();
#pragma unroll
    for (int kk = 0; kk < 16; ++kk) {
      const float4 a = *reinterpret_cast<const float4*>(&As[kk][ty << 2]);
      const float4 b = *reinterpret_cast<const float4*>(&Bs[kk][tx << 2]);
      const float aa[4] = {a.x, a.y, a.z, a.w};
      const float bb[4] = {b.x, b.y, b.z, b.w};
#pragma unroll
      for (int i = 0; i < 4; ++i)
#pragma unroll
        for (int j = 0; j < 4; ++j) acc[i][j] = fmaf(aa[i], bb[j], acc[i][j]);
    }
  }
#pragma unroll
  for (int i = 0; i < 4; ++i)
#pragma unroll
    for (int j = 0; j < 4; ++j)
      atomicAdd(&C[(size_t)(m0 + (ty << 2) + i) * ldc + n0 + (tx << 2) + j], acc[i][j]);
}

// ---------- R init: R[:,0:128] = B_w (R is 1024 x 896, ld=896) ----------
__global__ __launch_bounds__(256) void rinit(const float* __restrict__ Bw, float* __restrict__ R)
{
  const int g = blockIdx.x * 256 + threadIdx.x;      // 131072 total
  R[(size_t)(g >> 7) * 896 + (g & 127)] = Bw[g];
}

// ---------- input transpose: inp (128 x 32768 row-major view) -> Ubf bf16 (LTRUNC+32768) x 128,
// ---------- time-major, rows [0,LTRUNC) are zero padding (pre-memset).
__global__ __launch_bounds__(256) void ubuild(const float* __restrict__ inp, __hip_bfloat16* __restrict__ Ubf)
{
  __shared__ float tile[64][65];
  const int t0 = blockIdx.x << 6, s0 = blockIdx.y << 6;
  const int tid = threadIdx.x;
#pragma unroll
  for (int i = 0; i < 16; ++i) {
    const int e = i * 256 + tid;
    const int sl = e >> 6, tl = e & 63;
    tile[sl][tl] = inp[(size_t)(s0 + sl) * NSTEPS + t0 + tl];
  }
  __syncthreads();
#pragma unroll
  for (int i = 0; i < 16; ++i) {
    const int e = i * 256 + tid;
    const int tl = e >> 6, sl = e & 63;
    Ubf[(size_t)(LTRUNC + t0 + tl) * 128 + s0 + sl] = __float2bfloat16(tile[sl][tl]);
  }
}

// ---------- Kbt build: Kbt (128 x KTOT bf16, row-major; row r, col d*128+s) = K_d[r,s]
// ---------- K_0 = D; K_d = Kfull block (m=(d-1)>>4, j=(d-1)&15), each block 128x128 row-major.
__global__ __launch_bounds__(256) void kbuild(const float* __restrict__ Kfull, const float* __restrict__ Dw,
                                              __hip_bfloat16* __restrict__ Kbt)
{
  const int d = blockIdx.x;
  const int tid = threadIdx.x;
  const float* src;
  if (d == 0) {
    src = Dw;
  } else {
    const int m = (d - 1) >> 4, j = (d - 1) & 15;
    src = Kfull + ((size_t)m * 2048 + j * 128) * 128;
  }
  for (int i = 0; i < 64; ++i) {
    const int e = i * 256 + tid;
    const int r = e >> 7, s = e & 127;
    Kbt[(size_t)r * KTOT + d * 128 + s] = __float2bfloat16(src[e]);
  }
}

// ---------- main conv GEMM: out(32768x128) = A_virt @ Kbt^T-stored ----------
// A_virt[t, d*128+s] = u_{t-d}[s] = Ubf[(LTRUNC + t - d)*128 + s]  (sliding window)
// B[d*128+s, r]      = K_d[r,s]   = Kbt[r*KTOT + d*128 + s]
// 128x128 tile / WG, 4 waves (2x2), 16x16x32 bf16 MFMA, BK=64, f32 accum.
__global__ __launch_bounds__(256) void conv_mfma(
    const __hip_bfloat16* __restrict__ Ubf,
    const __hip_bfloat16* __restrict__ Kbt,
    float* __restrict__ out)
{
  __shared__ __hip_bfloat16 As[128][72];   // [time_local][k_local], +8 pad
  __shared__ __hip_bfloat16 Bs[128][72];   // [rcol][k_local]
  const int tid = threadIdx.x;
  const int t0 = blockIdx.x << 7;
  const int lane = tid & 63;
  const int wave = tid >> 6;
  const int wm = wave & 1, wn = wave >> 1;
  const int l15 = lane & 15, lk = lane >> 4;
  const int sr = tid >> 3;                 // staging row 0..31
  const int sc = (tid & 7) << 3;           // staging col 0..56 (bf16 units)
  f32x4 acc[4][4] = {};

  for (int it = 0; it < KTOT / 64; ++it) {
    const int kk0 = it << 6;
    const int d = kk0 >> 7;                // delay block
    const int s0 = kk0 & 127;              // 0 or 64
    const __hip_bfloat16* srcA = Ubf + (size_t)(LTRUNC + t0 - d) * 128 + s0;
    const __hip_bfloat16* srcB = Kbt + kk0;
    float4 va[4], vb[4];
#pragma unroll
    for (int p = 0; p < 4; ++p) {
      const int row = (p << 5) + sr;
      va[p] = *reinterpret_cast<const float4*>(srcA + (size_t)row * 128 + sc);
      vb[p] = *reinterpret_cast<const float4*>(srcB + (size_t)row * KTOT + sc);
    }
    __syncthreads();                        // previous compute done before overwrite
#pragma unroll
    for (int p = 0; p < 4; ++p) {
      const int row = (p << 5) + sr;
      *reinterpret_cast<float4*>(&As[row][sc]) = va[p];
      *reinterpret_cast<float4*>(&Bs[row][sc]) = vb[p];
    }
    __syncthreads();
#pragma unroll
    for (int kh = 0; kh < 2; ++kh) {
      const int kb = (kh << 5) + (lk << 3); // lane's 8 consecutive k elems
      short8 a[4], b[4];
#pragma unroll
      for (int mi = 0; mi < 4; ++mi)
        a[mi] = *reinterpret_cast<const short8*>(&As[(wm << 6) + (mi << 4) + l15][kb]);
#pragma unroll
      for (int ni = 0; ni < 4; ++ni)
        b[ni] = *reinterpret_cast<const short8*>(&Bs[(wn << 6) + (ni << 4) + l15][kb]);
#pragma unroll
      for (int mi = 0; mi < 4; ++mi)
#pragma unroll
        for (int ni = 0; ni < 4; ++ni)
          acc[mi][ni] = __builtin_amdgcn_mfma_f32_16x16x32_bf16(a[mi], b[ni], acc[mi][ni], 0, 0, 0);
    }
  }
  // epilogue: C/D layout col = lane&15, row = 4*(lane>>4)+reg  [m89-verified]
#pragma unroll
  for (int mi = 0; mi < 4; ++mi)
#pragma unroll
    for (int ni = 0; ni < 4; ++ni) {
      const int rcol = (wn << 6) + (ni << 4) + l15;
#pragma unroll
      for (int rg = 0; rg < 4; ++rg) {
        const int t = t0 + (wm << 6) + (mi << 4) + (lk << 2) + rg;
        out[(size_t)t * 128 + rcol] = acc[mi][ni][rg];
      }
    }
}

extern "C" void kernel_launch(void* const* d_in, const int* in_sizes, int n_in,
                              void* d_out, int out_size, void* d_ws, size_t ws_size,
                              hipStream_t stream)
{
  const float* inp = (const float*)d_in[0];
  const float* Aw  = (const float*)d_in[1];
  const float* Bw  = (const float*)d_in[2];
  const float* Cw  = (const float*)d_in[3];
  const float* Dw  = (const float*)d_in[4];
  float* out = (float*)d_out;

  char* ws = (char*)d_ws;
  size_t off = 0;
  auto carve = [&](size_t bytes) { char* p = ws + off; off += (bytes + 255) & ~(size_t)255; return p; };
  float* QA = (float*)carve((size_t)1024 * 1024 * 4);           // A power ping
  float* QB = (float*)carve((size_t)1024 * 1024 * 4);           // A power pong
  float* G  = (float*)carve((size_t)2048 * 1024 * 4);           // G_j = C A^j, j=0..15 stacked rows
  float* R  = (float*)carve((size_t)1024 * 896 * 4);            // R_m = A^{16m} B, m=0..6 col blocks
  float* Kfull = (float*)carve((size_t)7 * 2048 * 128 * 4);     // G @ R_m batched
  __hip_bfloat16* Kbt = (__hip_bfloat16*)carve((size_t)128 * KTOT * 2);
  __hip_bfloat16* Ubf = (__hip_bfloat16*)carve((size_t)(LTRUNC + NSTEPS) * 128 * 2);
  (void)ws_size; (void)in_sizes; (void)n_in; (void)out_size;

  auto gemm = [&](const float* A, const float* B, float* C, int M, int N, int K,
                  int lda, int ldb, int ldc, int nbatch, long bsB, long bsC) {
    dim3 grid(N / 64, M / 64, 4 * nbatch);
    gemm_f32<<<grid, 256, 0, stream>>>(A, B, C, K, lda, ldb, ldc, 4, bsB, bsC);
  };
  const size_t MB4 = (size_t)1024 * 1024 * 4;

  // ---- input transpose to time-major bf16, with LTRUNC zero rows of left padding
  hipMemsetAsync(Ubf, 0, (size_t)LTRUNC * 128 * 2, stream);
  ubuild<<<dim3(NSTEPS / 64, 2), 256, 0, stream>>>(inp, Ubf);

  // ---- G doubling: G_{j+2^s} = G_j @ A^{2^s}, interleaved with squarings
  hipMemsetAsync(G + (size_t)128 * 1024, 0, (size_t)(2048 - 128) * 1024 * 4, stream);
  hipMemcpyAsync(G, Cw, (size_t)128 * 1024 * 4, hipMemcpyDeviceToDevice, stream);
  hipMemsetAsync(R, 0, (size_t)1024 * 896 * 4, stream);
  rinit<<<512, 256, 0, stream>>>(Bw, R);

  gemm(G, Aw, G + (size_t)128 * 1024, 128, 1024, 1024, 1024, 1024, 1024, 1, 0, 0);   // G1
  hipMemsetAsync(QA, 0, MB4, stream);
  gemm(Aw, Aw, QA, 1024, 1024, 1024, 1024, 1024, 1024, 1, 0, 0);                     // A^2
  gemm(G, QA, G + (size_t)256 * 1024, 256, 1024, 1024, 1024, 1024, 1024, 1, 0, 0);   // G2,3
  hipMemsetAsync(QB, 0, MB4, stream);
  gemm(QA, QA, QB, 1024, 1024, 1024, 1024, 1024, 1024, 1, 0, 0);                     // A^4
  gemm(G, QB, G + (size_t)512 * 1024, 512, 1024, 1024, 1024, 1024, 1024, 1, 0, 0);   // G4..7
  hipMemsetAsync(QA, 0, MB4, stream);
  gemm(QB, QB, QA, 1024, 1024, 1024, 1024, 1024, 1024, 1, 0, 0);                     // A^8
  gemm(G, QA, G + (size_t)1024 * 1024, 1024, 1024, 1024, 1024, 1024, 1024, 1, 0, 0); // G8..15
  hipMemsetAsync(QB, 0, MB4, stream);
  gemm(QA, QA, QB, 1024, 1024, 1024, 1024, 1024, 1024, 1, 0, 0);                     // A^16

  // ---- R doubling: R_{m+2^s} = A^{16*2^s} @ R_m (col blocks of R, ld=896)
  gemm(QB, R, R + 128, 1024, 128, 1024, 1024, 896, 896, 1, 0, 0);                    // R1
  hipMemsetAsync(QA, 0, MB4, stream);
  gemm(QB, QB, QA, 1024, 1024, 1024, 1024, 1024, 1024, 1, 0, 0);                     // A^32
  gemm(QA, R, R + 256, 1024, 256, 1024, 1024, 896, 896, 1, 0, 0);                    // R2,3
  hipMemsetAsync(QB, 0, MB4, stream);
  gemm(QA, QA, QB, 1024, 1024, 1024, 1024, 1024, 1024, 1, 0, 0);                     // A^64
  gemm(QB, R, R + 512, 1024, 384, 1024, 1024, 896, 896, 1, 0, 0);                    // R4,5,6

  // ---- K_d = G_j @ R_m, batched over m (7 batches)
  hipMemsetAsync(Kfull, 0, (size_t)7 * 2048 * 128 * 4, stream);
  gemm(G, R, Kfull, 2048, 128, 1024, 1024, 896, 128, 7, 128, (long)2048 * 128);

  // ---- pack kernel bank to bf16 (transposed-contiguous for MFMA B-frags)
  kbuild<<<NDBLK, 256, 0, stream>>>(Kfull, Dw, Kbt);

  // ---- main truncated convolution (writes every output element)
  conv_mfma<<<NSTEPS / 128, 256, 0, stream>>>(Ubf, Kbt, out);
}

// Round 2
// 860.257 us; speedup vs baseline: 1.6417x; 1.6417x over previous
//
#include <hip/hip_runtime.h>
#include <hip/hip_bf16.h>

// LinearStateSpace via truncated convolution:
//   y_t = D u_t + sum_{d=1..112} (C A^{d-1} B) u_{t-d},  rho(A)=0.9 -> tail ~1e-3.
// Precompute of the kernel bank runs in bf16x2 (hi+lo split, 3-term MFMA products,
// ~2^-16 relative error). Main conv = m97-structure MFMA GEMM with sliding-window A.

#define NSTEPS 32768
#define LTRUNC 112
#define NDBLK  (LTRUNC + 1)
#define KTOT   (NDBLK * 128)     // 14464
#define SPLITK 4

typedef __attribute__((ext_vector_type(8))) short short8;
typedef __attribute__((ext_vector_type(4))) float f32x4;
typedef __hip_bfloat16 bf16;

__device__ __forceinline__ void gload16(const void* g, void* l) {
  __builtin_amdgcn_global_load_lds(
      (const __attribute__((address_space(1))) void*)g,
      (__attribute__((address_space(3))) void*)l, 16, 0, 0);
}

__device__ __forceinline__ void split1(float x, bf16& h, bf16& l) {
  h = __float2bfloat16(x);
  l = __float2bfloat16(x - __bfloat162float(h));
}

// ---------- f32 -> (hi,lo) bf16, row-major passthrough ----------
__global__ __launch_bounds__(256) void split_rm(const float* __restrict__ src,
                                                bf16* __restrict__ hi, bf16* __restrict__ lo) {
  const int i = (blockIdx.x * 256 + threadIdx.x) * 4;
  const float4 v = *reinterpret_cast<const float4*>(src + i);
  const float vv[4] = {v.x, v.y, v.z, v.w};
#pragma unroll
  for (int j = 0; j < 4; ++j) { bf16 h, l; split1(vv[j], h, l); hi[i + j] = h; lo[i + j] = l; }
}

// ---------- f32 (RxC) -> (hi,lo) bf16 transposed (CxR) ----------
__global__ __launch_bounds__(256) void split_cm(const float* __restrict__ src,
                                                bf16* __restrict__ hi, bf16* __restrict__ lo,
                                                int R, int C) {
  __shared__ float t[64][65];
  const int r0 = blockIdx.y << 6, c0 = blockIdx.x << 6;
  const int tid = threadIdx.x;
#pragma unroll
  for (int i = 0; i < 16; ++i) {
    const int e = i * 256 + tid, rl = e >> 6, cl = e & 63;
    t[rl][cl] = src[(size_t)(r0 + rl) * C + c0 + cl];
  }
  __syncthreads();
#pragma unroll
  for (int i = 0; i < 16; ++i) {
    const int e = i * 256 + tid, cl = e >> 6, rl = e & 63;
    bf16 h, l; split1(t[rl][cl], h, l);
    hi[(size_t)(c0 + cl) * R + r0 + rl] = h;
    lo[(size_t)(c0 + cl) * R + r0 + rl] = l;
  }
}

// ---------- input transpose: inp(128 x 32768) -> Ubf bf16 (LTRUNC+32768) x 128 ----------
__global__ __launch_bounds__(256) void ubuild(const float* __restrict__ inp, bf16* __restrict__ Ubf) {
  __shared__ float tile[64][65];
  const int t0 = blockIdx.x << 6, s0 = blockIdx.y << 6;
  const int tid = threadIdx.x;
#pragma unroll
  for (int i = 0; i < 16; ++i) {
    const int e = i * 256 + tid, sl = e >> 6, tl = e & 63;
    tile[sl][tl] = inp[(size_t)(s0 + sl) * NSTEPS + t0 + tl];
  }
  __syncthreads();
#pragma unroll
  for (int i = 0; i < 16; ++i) {
    const int e = i * 256 + tid, tl = e >> 6, sl = e & 63;
    Ubf[(size_t)(LTRUNC + t0 + tl) * 128 + s0 + sl] = __float2bfloat16(tile[sl][tl]);
  }
}

// ---------- Kbt d=0 block = bf16(D) ----------
__global__ __launch_bounds__(256) void dinit(const float* __restrict__ Dw, bf16* __restrict__ Kbt) {
  const int e = blockIdx.x * 256 + threadIdx.x;   // 16384
  const int r = e >> 7, s = e & 127;
  Kbt[(size_t)r * KTOT + s] = __float2bfloat16(Dw[e]);
}

// ---------- bf16x2 GEMM: C = (Ahi+Alo)(Bhi+Blo), A row-major [M][K], B col-major [N][K].
// ---------- Outputs (any subset): C row-major hi/lo, C^T ("cm") hi/lo, or Kbt-special (hi only).
__global__ __launch_bounds__(256) void gemm2(
    const bf16* __restrict__ Ahi, const bf16* __restrict__ Alo, int lda,
    const bf16* __restrict__ Bhi, const bf16* __restrict__ Blo, int ldb, long bsB,
    bf16* __restrict__ Crh, bf16* __restrict__ Crl, int ldcr,
    bf16* __restrict__ Cch, bf16* __restrict__ Ccl, int ldcc,
    bf16* __restrict__ Kbt, int K)
{
  __shared__ __align__(16) bf16 sAh[128 * 64];
  __shared__ __align__(16) bf16 sAl[128 * 64];
  __shared__ __align__(16) bf16 sBh[128 * 64];
  __shared__ __align__(16) bf16 sBl[128 * 64];
  const int tid = threadIdx.x, lane = tid & 63, wave = tid >> 6;
  const int wm = wave & 1, wn = wave >> 1, l15 = lane & 15, lk = lane >> 4;
  const int m0 = blockIdx.y << 7, n0 = blockIdx.x << 7, z = blockIdx.z;
  const bf16* bh = Bhi + (size_t)z * bsB;
  const bf16* bl = Blo + (size_t)z * bsB;
  const int srow = tid >> 3, sc8 = (tid & 7) << 3;
  f32x4 acc[4][4] = {};
  for (int k0 = 0; k0 < K; k0 += 64) {
    __syncthreads();
#pragma unroll
    for (int p = 0; p < 4; ++p) {
      const int row = (p << 5) + srow;
      const size_t aoff = (size_t)(m0 + row) * lda + k0 + sc8;
      const size_t boff = (size_t)(n0 + row) * ldb + k0 + sc8;
      const int loff = row * 64 + sc8;
      gload16(Ahi + aoff, sAh + loff);
      gload16(Alo + aoff, sAl + loff);
      gload16(bh + boff, sBh + loff);
      gload16(bl + boff, sBl + loff);
    }
    __syncthreads();
#pragma unroll
    for (int kh = 0; kh < 2; ++kh) {
      const int kb = (kh << 5) + (lk << 3);
      short8 ah[4], al[4], bhv[4], blv[4];
#pragma unroll
      for (int mi = 0; mi < 4; ++mi) {
        const int r = ((wm << 6) + (mi << 4) + l15) * 64 + kb;
        ah[mi] = *reinterpret_cast<const short8*>(sAh + r);
        al[mi] = *reinterpret_cast<const short8*>(sAl + r);
      }
#pragma unroll
      for (int ni = 0; ni < 4; ++ni) {
        const int r = ((wn << 6) + (ni << 4) + l15) * 64 + kb;
        bhv[ni] = *reinterpret_cast<const short8*>(sBh + r);
        blv[ni] = *reinterpret_cast<const short8*>(sBl + r);
      }
#pragma unroll
      for (int mi = 0; mi < 4; ++mi)
#pragma unroll
        for (int ni = 0; ni < 4; ++ni) {
          acc[mi][ni] = __builtin_amdgcn_mfma_f32_16x16x32_bf16(ah[mi], bhv[ni], acc[mi][ni], 0, 0, 0);
          acc[mi][ni] = __builtin_amdgcn_mfma_f32_16x16x32_bf16(ah[mi], blv[ni], acc[mi][ni], 0, 0, 0);
          acc[mi][ni] = __builtin_amdgcn_mfma_f32_16x16x32_bf16(al[mi], bhv[ni], acc[mi][ni], 0, 0, 0);
        }
    }
  }
#pragma unroll
  for (int mi = 0; mi < 4; ++mi)
#pragma unroll
    for (int ni = 0; ni < 4; ++ni) {
      const int cl = (wn << 6) + (ni << 4) + l15;
#pragma unroll
      for (int rg = 0; rg < 4; ++rg) {
        const int rl = (wm << 6) + (mi << 4) + (lk << 2) + rg;
        const float c = acc[mi][ni][rg];
        bf16 h, l; split1(c, h, l);
        if (Crh) {
          Crh[(size_t)(m0 + rl) * ldcr + n0 + cl] = h;
          Crl[(size_t)(m0 + rl) * ldcr + n0 + cl] = l;
        }
        if (Cch) {
          Cch[(size_t)(n0 + cl) * ldcc + m0 + rl] = h;
          Ccl[(size_t)(n0 + cl) * ldcc + m0 + rl] = l;
        }
        if (Kbt) {
          const int d = 1 + blockIdx.y + 16 * z;
          Kbt[(size_t)rl * KTOT + (size_t)d * 128 + cl] = h;
        }
      }
    }
}

// ---------- main conv: out(32768x128) += A_virt @ Kbt, split-K over delay blocks ----------
__global__ __launch_bounds__(256) void conv_mfma(
    const bf16* __restrict__ Ubf, const bf16* __restrict__ Kbt, float* __restrict__ out)
{
  __shared__ __align__(16) bf16 As[128 * 64];
  __shared__ __align__(16) bf16 Bs[128 * 64];
  const int tid = threadIdx.x;
  const int t0 = blockIdx.x << 7;
  const int lane = tid & 63, wave = tid >> 6;
  const int wm = wave & 1, wn = wave >> 1;
  const int l15 = lane & 15, lk = lane >> 4;
  const int srow = tid >> 3, sc8 = (tid & 7) << 3;
  const int ntot = KTOT / 64;                       // 226
  const int sb = (blockIdx.y * ntot) / SPLITK;
  const int se = ((blockIdx.y + 1) * ntot) / SPLITK;
  f32x4 acc[4][4] = {};
  for (int it = sb; it < se; ++it) {
    const int kk0 = it << 6;
    const int d = kk0 >> 7, s0 = kk0 & 127;
    const bf16* srcA = Ubf + (size_t)(LTRUNC + t0 - d) * 128 + s0;
    const bf16* srcB = Kbt + kk0;
    __syncthreads();                                // LDS free (prev compute done)
#pragma unroll
    for (int p = 0; p < 4; ++p) {
      const int row = (p << 5) + srow;
      gload16(srcA + (size_t)row * 128 + sc8, As + row * 64 + sc8);
      gload16(srcB + (size_t)row * KTOT + sc8, Bs + row * 64 + sc8);
    }
    __syncthreads();                                // drains vmcnt(0): tiles landed
#pragma unroll
    for (int kh = 0; kh < 2; ++kh) {
      const int kb = (kh << 5) + (lk << 3);
      short8 a[4], b[4];
#pragma unroll
      for (int mi = 0; mi < 4; ++mi)
        a[mi] = *reinterpret_cast<const short8*>(As + ((wm << 6) + (mi << 4) + l15) * 64 + kb);
#pragma unroll
      for (int ni = 0; ni < 4; ++ni)
        b[ni] = *reinterpret_cast<const short8*>(Bs + ((wn << 6) + (ni << 4) + l15) * 64 + kb);
#pragma unroll
      for (int mi = 0; mi < 4; ++mi)
#pragma unroll
        for (int ni = 0; ni < 4; ++ni)
          acc[mi][ni] = __builtin_amdgcn_mfma_f32_16x16x32_bf16(a[mi], b[ni], acc[mi][ni], 0, 0, 0);
    }
  }
  // epilogue: C/D layout col = lane&15, row = 4*(lane>>4)+reg; atomic split-K combine
#pragma unroll
  for (int mi = 0; mi < 4; ++mi)
#pragma unroll
    for (int ni = 0; ni < 4; ++ni) {
      const int rcol = (wn << 6) + (ni << 4) + l15;
#pragma unroll
      for (int rg = 0; rg < 4; ++rg) {
        const int t = t0 + (wm << 6) + (mi << 4) + (lk << 2) + rg;
        atomicAdd(out + (size_t)t * 128 + rcol, acc[mi][ni][rg]);
      }
    }
}

extern "C" void kernel_launch(void* const* d_in, const int* in_sizes, int n_in,
                              void* d_out, int out_size, void* d_ws, size_t ws_size,
                              hipStream_t stream)
{
  const float* inp = (const float*)d_in[0];
  const float* Aw  = (const float*)d_in[1];
  const float* Bw  = (const float*)d_in[2];
  const float* Cw  = (const float*)d_in[3];
  const float* Dw  = (const float*)d_in[4];
  float* out = (float*)d_out;
  (void)in_sizes; (void)n_in; (void)out_size; (void)ws_size;

  char* ws = (char*)d_ws;
  size_t off = 0;
  auto carve = [&](size_t bytes) { char* p = ws + off; off += (bytes + 255) & ~(size_t)255; return p; };
  const size_t M1 = (size_t)1024 * 1024;
  // A (original) and power ping/pong, each in 4 layouts (hi/lo x rm/cm)
  bf16* Ahr = (bf16*)carve(M1 * 2); bf16* Alr = (bf16*)carve(M1 * 2);
  bf16* Ahc = (bf16*)carve(M1 * 2); bf16* Alc = (bf16*)carve(M1 * 2);
  bf16* QAhr = (bf16*)carve(M1 * 2); bf16* QAlr = (bf16*)carve(M1 * 2);
  bf16* QAhc = (bf16*)carve(M1 * 2); bf16* QAlc = (bf16*)carve(M1 * 2);
  bf16* QBhr = (bf16*)carve(M1 * 2); bf16* QBlr = (bf16*)carve(M1 * 2);
  bf16* QBhc = (bf16*)carve(M1 * 2); bf16* QBlc = (bf16*)carve(M1 * 2);
  bf16* Ghr = (bf16*)carve((size_t)2048 * 1024 * 2);   // G_j = C A^j rows, rm only
  bf16* Glr = (bf16*)carve((size_t)2048 * 1024 * 2);
  bf16* Rth = (bf16*)carve((size_t)896 * 1024 * 2);    // R^T rows (cm of R), 7 blocks of 128
  bf16* Rtl = (bf16*)carve((size_t)896 * 1024 * 2);
  bf16* Kbt = (bf16*)carve((size_t)128 * KTOT * 2);
  bf16* Ubf = (bf16*)carve((size_t)(LTRUNC + NSTEPS) * 128 * 2);

  auto g2 = [&](const bf16* Ah, const bf16* Al, int lda,
                const bf16* Bh, const bf16* Bl, int ldb, long bsB,
                bf16* crh, bf16* crl, int ldcr,
                bf16* cch, bf16* ccl, int ldcc,
                bf16* kbt, int M, int N, int K, int nb) {
    gemm2<<<dim3(N / 128, M / 128, nb), 256, 0, stream>>>(
        Ah, Al, lda, Bh, Bl, ldb, bsB, crh, crl, ldcr, cch, ccl, ldcc, kbt, K);
  };

  // ---- input transpose (pad rows zeroed) ----
  hipMemsetAsync(Ubf, 0, (size_t)LTRUNC * 128 * 2, stream);
  ubuild<<<dim3(NSTEPS / 64, 2), 256, 0, stream>>>(inp, Ubf);

  // ---- splits of the raw weights ----
  split_rm<<<1024, 256, 0, stream>>>(Aw, Ahr, Alr);                  // A row-major
  split_cm<<<dim3(16, 16), 256, 0, stream>>>(Aw, Ahc, Alc, 1024, 1024); // A^T
  split_rm<<<128, 256, 0, stream>>>(Cw, Ghr, Glr);                   // G_0 = C
  split_cm<<<dim3(2, 16), 256, 0, stream>>>(Bw, Rth, Rtl, 1024, 128);  // R_0^T = B^T
  dinit<<<64, 256, 0, stream>>>(Dw, Kbt);                            // K_0 = D

  // ---- power/G/R chain (all bf16x2 MFMA) ----
  // A^2 -> QA
  g2(Ahr, Alr, 1024, Ahc, Alc, 1024, 0, QAhr, QAlr, 1024, QAhc, QAlc, 1024, nullptr, 1024, 1024, 1024, 1);
  // G1 = G0 A
  g2(Ghr, Glr, 1024, Ahc, Alc, 1024, 0, Ghr + 128 * 1024, Glr + 128 * 1024, 1024, nullptr, nullptr, 0, nullptr, 128, 1024, 1024, 1);
  // G2,3 = [G0;G1] A^2
  g2(Ghr, Glr, 1024, QAhc, QAlc, 1024, 0, Ghr + 256 * 1024, Glr + 256 * 1024, 1024, nullptr, nullptr, 0, nullptr, 256, 1024, 1024, 1);
  // A^4 -> QB
  g2(QAhr, QAlr, 1024, QAhc, QAlc, 1024, 0, QBhr, QBlr, 1024, QBhc, QBlc, 1024, nullptr, 1024, 1024, 1024, 1);
  // G4..7 = [G0..G3] A^4
  g2(Ghr, Glr, 1024, QBhc, QBlc, 1024, 0, Ghr + 512 * 1024, Glr + 512 * 1024, 1024, nullptr, nullptr, 0, nullptr, 512, 1024, 1024, 1);
  // A^8 -> QA (A^2 dead)
  g2(QBhr, QBlr, 1024, QBhc, QBlc, 1024, 0, QAhr, QAlr, 1024, QAhc, QAlc, 1024, nullptr, 1024, 1024, 1024, 1);
  // G8..15 = [G0..G7] A^8
  g2(Ghr, Glr, 1024, QAhc, QAlc, 1024, 0, Ghr + (size_t)1024 * 1024, Glr + (size_t)1024 * 1024, 1024, nullptr, nullptr, 0, nullptr, 1024, 1024, 1024, 1);
  // A^16 -> QB (A^4 dead)
  g2(QAhr, QAlr, 1024, QAhc, QAlc, 1024, 0, QBhr, QBlr, 1024, QBhc, QBlc, 1024, nullptr, 1024, 1024, 1024, 1);
  // R1 = A^16 R0  (cm out -> Rt rows 128..255)
  g2(QBhr, QBlr, 1024, Rth, Rtl, 1024, 0, nullptr, nullptr, 0, Rth + 128 * 1024, Rtl + 128 * 1024, 1024, nullptr, 1024, 128, 1024, 1);
  // A^32 -> QA (A^8 dead)
  g2(QBhr, QBlr, 1024, QBhc, QBlc, 1024, 0, QAhr, QAlr, 1024, QAhc, QAlc, 1024, nullptr, 1024, 1024, 1024, 1);
  // R2,3 = A^32 [R0 R1]
  g2(QAhr, QAlr, 1024, Rth, Rtl, 1024, 0, nullptr, nullptr, 0, Rth + 256 * 1024, Rtl + 256 * 1024, 1024, nullptr, 1024, 256, 1024, 1);
  // A^64 -> QB (A^16 dead)
  g2(QAhr, QAlr, 1024, QAhc, QAlc, 1024, 0, QBhr, QBlr, 1024, QBhc, QBlc, 1024, nullptr, 1024, 1024, 1024, 1);
  // R4,5,6 = A^64 [R0 R1 R2]
  g2(QBhr, QBlr, 1024, Rth, Rtl, 1024, 0, nullptr, nullptr, 0, Rth + 512 * 1024, Rtl + 512 * 1024, 1024, nullptr, 1024, 384, 1024, 1);
  // K_d (d=1..112) = G_j R_m -> Kbt directly (bf16 hi only), batched over m
  g2(Ghr, Glr, 1024, Rth, Rtl, 1024, (long)128 * 1024, nullptr, nullptr, 0, nullptr, nullptr, 0, Kbt, 2048, 128, 1024, 7);

  // ---- main conv ----
  hipMemsetAsync(out, 0, (size_t)NSTEPS * 128 * 4, stream);
  conv_mfma<<<dim3(NSTEPS / 128, SPLITK), 256, 0, stream>>>(Ubf, Kbt, out);
}

// Round 3
// 563.498 us; speedup vs baseline: 2.5064x; 1.5266x over previous
//
#include <hip/hip_runtime.h>
#include <hip/hip_bf16.h>

// LinearStateSpace via truncated convolution:
//   y_t = D u_t + sum_{d=1..112} (C A^{d-1} B) u_{t-d},  rho(A)=0.9 -> tail ~1e-3.
// Precompute: bf16x2 (hi+lo, 3-term) batched descriptor GEMMs, split-K=4 atomic
// into f32 slab + pack pass. Main conv: 128x128-tile MFMA GEMM, sliding-window A,
// XOR-swizzled LDS (pre-swizzled global source + swizzled ds_read; rule #21).

#define NSTEPS 32768
#define LTRUNC 112
#define NDBLK  (LTRUNC + 1)
#define KTOT   (NDBLK * 128)     // 14464
#define SPLITK 4                 // conv split-K
#define CSPLIT 4                 // chain split-K

typedef __attribute__((ext_vector_type(8))) short short8;
typedef __attribute__((ext_vector_type(4))) float f32x4;
typedef __hip_bfloat16 bf16;

__device__ __forceinline__ void gload16(const void* g, void* l) {
  __builtin_amdgcn_global_load_lds(
      (const __attribute__((address_space(1))) void*)g,
      (__attribute__((address_space(3))) void*)l, 16, 0, 0);
}

__device__ __forceinline__ void split1(float x, bf16& h, bf16& l) {
  h = __float2bfloat16(x);
  l = __float2bfloat16(x - __bfloat162float(h));
}

// ---------- f32 -> (hi,lo) bf16, row-major ----------
__global__ __launch_bounds__(256) void split_rm(const float* __restrict__ src,
                                                bf16* __restrict__ hi, bf16* __restrict__ lo) {
  const int i = (blockIdx.x * 256 + threadIdx.x) * 4;
  const float4 v = *reinterpret_cast<const float4*>(src + i);
  const float vv[4] = {v.x, v.y, v.z, v.w};
#pragma unroll
  for (int j = 0; j < 4; ++j) { bf16 h, l; split1(vv[j], h, l); hi[i + j] = h; lo[i + j] = l; }
}

// ---------- f32 (RxC) -> (hi,lo) bf16 transposed (CxR) ----------
__global__ __launch_bounds__(256) void split_cm(const float* __restrict__ src,
                                                bf16* __restrict__ hi, bf16* __restrict__ lo,
                                                int R, int C) {
  __shared__ float t[64][65];
  const int r0 = blockIdx.y << 6, c0 = blockIdx.x << 6;
  const int tid = threadIdx.x;
#pragma unroll
  for (int i = 0; i < 16; ++i) {
    const int e = i * 256 + tid, rl = e >> 6, cl = e & 63;
    t[rl][cl] = src[(size_t)(r0 + rl) * C + c0 + cl];
  }
  __syncthreads();
#pragma unroll
  for (int i = 0; i < 16; ++i) {
    const int e = i * 256 + tid, cl = e >> 6, rl = e & 63;
    bf16 h, l; split1(t[rl][cl], h, l);
    hi[(size_t)(c0 + cl) * R + r0 + rl] = h;
    lo[(size_t)(c0 + cl) * R + r0 + rl] = l;
  }
}

// ---------- input transpose: inp(128 x 32768) -> Ubf bf16 (LTRUNC+32768) x 128 ----------
__global__ __launch_bounds__(256) void ubuild(const float* __restrict__ inp, bf16* __restrict__ Ubf) {
  __shared__ float tile[64][65];
  const int t0 = blockIdx.x << 6, s0 = blockIdx.y << 6;
  const int tid = threadIdx.x;
#pragma unroll
  for (int i = 0; i < 16; ++i) {
    const int e = i * 256 + tid, sl = e >> 6, tl = e & 63;
    tile[sl][tl] = inp[(size_t)(s0 + sl) * NSTEPS + t0 + tl];
  }
  __syncthreads();
#pragma unroll
  for (int i = 0; i < 16; ++i) {
    const int e = i * 256 + tid, tl = e >> 6, sl = e & 63;
    Ubf[(size_t)(LTRUNC + t0 + tl) * 128 + s0 + sl] = __float2bfloat16(tile[sl][tl]);
  }
}

// ---------- Kbt d=0 block = bf16(D) ----------
__global__ __launch_bounds__(256) void dinit(const float* __restrict__ Dw, bf16* __restrict__ Kbt) {
  const int e = blockIdx.x * 256 + threadIdx.x;   // 16384
  const int r = e >> 7, s = e & 127;
  Kbt[(size_t)r * KTOT + s] = __float2bfloat16(Dw[e]);
}

// ---------- batched descriptor chain GEMM (bf16x2, 3-term), split-K=4, atomic f32 slab ----------
struct GDesc {
  const bf16 *Ah, *Al;   // A row-major M x 1024, ld 1024
  const bf16 *Bh, *Bl;   // B col-major (N rows x 1024), ld 1024
  float* slab;           // M x N f32, pre-zeroed, atomic accumulate
  int mt, nt, base;      // 128-tiles, WG prefix
};
struct GBatch { GDesc d[6]; int n; };

__global__ __launch_bounds__(256) void chain_gemm(GBatch gb)
{
  __shared__ __align__(16) bf16 sAh[128 * 64];
  __shared__ __align__(16) bf16 sAl[128 * 64];
  __shared__ __align__(16) bf16 sBh[128 * 64];
  __shared__ __align__(16) bf16 sBl[128 * 64];
  const int bid = blockIdx.x;
  int di = 0;
  while (di + 1 < gb.n && bid >= gb.d[di + 1].base) ++di;
  const GDesc g = gb.d[di];
  const int t = bid - g.base;
  const int ntile = g.mt * g.nt;
  const int split = t / ntile;
  const int tile = t - split * ntile;
  const int my = tile / g.nt, nx = tile - my * g.nt;
  const int m0 = my << 7, n0 = nx << 7;

  const int tid = threadIdx.x, lane = tid & 63, wave = tid >> 6;
  const int wm = wave & 1, wn = wave >> 1, l15 = lane & 15, lk = lane >> 4;
  const int srow = tid >> 3, sc8 = (tid & 7) << 3;
  const int g8 = (((tid & 7) ^ (srow & 7)) << 3);           // pre-swizzled source chunk
  const int ca0 = ((lk ^ (l15 & 7)) << 3);                  // swizzled read offs, kh=0
  const int ca1 = (((4 + lk) ^ (l15 & 7)) << 3);            // kh=1
  f32x4 acc[4][4] = {};

  const int k0beg = split << 8;                             // split * 256
  for (int ks = 0; ks < 4; ++ks) {
    const int k0 = k0beg + (ks << 6);
    __syncthreads();
#pragma unroll
    for (int p = 0; p < 4; ++p) {
      const int row = (p << 5) + srow;
      const int loff = row * 64 + sc8;
      const size_t aoff = (size_t)(m0 + row) * 1024 + k0 + g8;
      const size_t boff = (size_t)(n0 + row) * 1024 + k0 + g8;
      gload16(g.Ah + aoff, sAh + loff);
      gload16(g.Al + aoff, sAl + loff);
      gload16(g.Bh + boff, sBh + loff);
      gload16(g.Bl + boff, sBl + loff);
    }
    __syncthreads();
#pragma unroll
    for (int kh = 0; kh < 2; ++kh) {
      const int cb = kh ? ca1 : ca0;
      short8 ah[4], al[4], bh[4], bl[4];
#pragma unroll
      for (int mi = 0; mi < 4; ++mi) {
        const int r = ((wm << 6) + (mi << 4) + l15) * 64 + cb;
        ah[mi] = *reinterpret_cast<const short8*>(sAh + r);
        al[mi] = *reinterpret_cast<const short8*>(sAl + r);
      }
#pragma unroll
      for (int ni = 0; ni < 4; ++ni) {
        const int r = ((wn << 6) + (ni << 4) + l15) * 64 + cb;
        bh[ni] = *reinterpret_cast<const short8*>(sBh + r);
        bl[ni] = *reinterpret_cast<const short8*>(sBl + r);
      }
#pragma unroll
      for (int mi = 0; mi < 4; ++mi)
#pragma unroll
        for (int ni = 0; ni < 4; ++ni) {
          acc[mi][ni] = __builtin_amdgcn_mfma_f32_16x16x32_bf16(ah[mi], bh[ni], acc[mi][ni], 0, 0, 0);
          acc[mi][ni] = __builtin_amdgcn_mfma_f32_16x16x32_bf16(ah[mi], bl[ni], acc[mi][ni], 0, 0, 0);
          acc[mi][ni] = __builtin_amdgcn_mfma_f32_16x16x32_bf16(al[mi], bh[ni], acc[mi][ni], 0, 0, 0);
        }
    }
  }
  const int ldc = g.nt << 7;
#pragma unroll
  for (int mi = 0; mi < 4; ++mi)
#pragma unroll
    for (int ni = 0; ni < 4; ++ni) {
      const int cl = (wn << 6) + (ni << 4) + l15;
#pragma unroll
      for (int rg = 0; rg < 4; ++rg) {
        const int rl = (wm << 6) + (mi << 4) + (lk << 2) + rg;
        atomicAdd(g.slab + (size_t)(m0 + rl) * ldc + n0 + cl, acc[mi][ni][rg]);
      }
    }
}

// ---------- pack: f32 slab -> bf16 hi/lo row-major and/or col-major and/or Kbt ----------
struct PDesc {
  const float* slab;
  bf16 *rh, *rl, *ch, *cl, *kb;
  int M, N, ldr, ldc, dbase, base;   // base = block prefix (1024 elems / block)
};
struct PBatch { PDesc d[6]; int n; };

__global__ __launch_bounds__(256) void pack(PBatch pb)
{
  const int bid = blockIdx.x;
  int di = 0;
  while (di + 1 < pb.n && bid >= pb.d[di + 1].base) ++di;
  const PDesc p = pb.d[di];
  const int e4 = (bid - p.base) * 1024 + threadIdx.x * 4;
  const int row = e4 / p.N, col = e4 - row * p.N;
  const float4 v = *reinterpret_cast<const float4*>(p.slab + (size_t)row * p.N + col);
  const float vv[4] = {v.x, v.y, v.z, v.w};
#pragma unroll
  for (int j = 0; j < 4; ++j) {
    bf16 h, l; split1(vv[j], h, l);
    if (p.rh) {
      p.rh[(size_t)row * p.ldr + col + j] = h;
      p.rl[(size_t)row * p.ldr + col + j] = l;
    }
    if (p.ch) {
      p.ch[(size_t)(col + j) * p.ldc + row] = h;
      p.cl[(size_t)(col + j) * p.ldc + row] = l;
    }
    if (p.kb) {
      const int d = p.dbase + (row >> 7);
      p.kb[(size_t)(row & 127) * KTOT + (size_t)d * 128 + col + j] = h;
    }
  }
}

// ---------- main conv: out(32768x128) += A_virt @ Kbt, split-K, swizzled LDS ----------
__global__ __launch_bounds__(256) void conv_mfma(
    const bf16* __restrict__ Ubf, const bf16* __restrict__ Kbt, float* __restrict__ out)
{
  __shared__ __align__(16) bf16 As[128 * 64];
  __shared__ __align__(16) bf16 Bs[128 * 64];
  const int tid = threadIdx.x;
  const int t0 = blockIdx.x << 7;
  const int lane = tid & 63, wave = tid >> 6;
  const int wm = wave & 1, wn = wave >> 1;
  const int l15 = lane & 15, lk = lane >> 4;
  const int srow = tid >> 3, sc8 = (tid & 7) << 3;
  const int g8 = (((tid & 7) ^ (srow & 7)) << 3);
  const int ca0 = ((lk ^ (l15 & 7)) << 3);
  const int ca1 = (((4 + lk) ^ (l15 & 7)) << 3);
  const int ntot = KTOT / 64;                       // 226
  const int sb = (blockIdx.y * ntot) / SPLITK;
  const int se = ((blockIdx.y + 1) * ntot) / SPLITK;
  f32x4 acc[4][4] = {};
  for (int it = sb; it < se; ++it) {
    const int kk0 = it << 6;
    const int d = kk0 >> 7, s0 = kk0 & 127;
    const bf16* srcA = Ubf + (size_t)(LTRUNC + t0 - d) * 128 + s0;
    const bf16* srcB = Kbt + kk0;
    __syncthreads();                                // LDS free (prev compute done)
#pragma unroll
    for (int p = 0; p < 4; ++p) {
      const int row = (p << 5) + srow;
      gload16(srcA + (size_t)row * 128 + g8, As + row * 64 + sc8);
      gload16(srcB + (size_t)row * KTOT + g8, Bs + row * 64 + sc8);
    }
    __syncthreads();                                // drains vmcnt(0): tiles landed
#pragma unroll
    for (int kh = 0; kh < 2; ++kh) {
      const int cb = kh ? ca1 : ca0;
      short8 a[4], b[4];
#pragma unroll
      for (int mi = 0; mi < 4; ++mi)
        a[mi] = *reinterpret_cast<const short8*>(As + ((wm << 6) + (mi << 4) + l15) * 64 + cb);
#pragma unroll
      for (int ni = 0; ni < 4; ++ni)
        b[ni] = *reinterpret_cast<const short8*>(Bs + ((wn << 6) + (ni << 4) + l15) * 64 + cb);
#pragma unroll
      for (int mi = 0; mi < 4; ++mi)
#pragma unroll
        for (int ni = 0; ni < 4; ++ni)
          acc[mi][ni] = __builtin_amdgcn_mfma_f32_16x16x32_bf16(a[mi], b[ni], acc[mi][ni], 0, 0, 0);
    }
  }
#pragma unroll
  for (int mi = 0; mi < 4; ++mi)
#pragma unroll
    for (int ni = 0; ni < 4; ++ni) {
      const int rcol = (wn << 6) + (ni << 4) + l15;
#pragma unroll
      for (int rg = 0; rg < 4; ++rg) {
        const int t = t0 + (wm << 6) + (mi << 4) + (lk << 2) + rg;
        atomicAdd(out + (size_t)t * 128 + rcol, acc[mi][ni][rg]);
      }
    }
}

// ---------- host-side level builder ----------
struct Builder {
  GBatch gb; PBatch pb;
  float* slab0; float* sp; int wg, blk;
  Builder(float* s) : gb{}, pb{}, slab0(s), sp(s), wg(0), blk(0) {}
  void add(const bf16* Ah, const bf16* Al, const bf16* Bh, const bf16* Bl,
           int mt, int nt,
           bf16* rh, bf16* rl, int ldr,
           bf16* ch, bf16* cl, int ldc,
           bf16* kb, int dbase) {
    const int i = gb.n;
    gb.d[i].Ah = Ah; gb.d[i].Al = Al; gb.d[i].Bh = Bh; gb.d[i].Bl = Bl;
    gb.d[i].slab = sp; gb.d[i].mt = mt; gb.d[i].nt = nt; gb.d[i].base = wg;
    pb.d[i].slab = sp; pb.d[i].rh = rh; pb.d[i].rl = rl; pb.d[i].ch = ch;
    pb.d[i].cl = cl; pb.d[i].kb = kb; pb.d[i].M = mt << 7; pb.d[i].N = nt << 7;
    pb.d[i].ldr = ldr; pb.d[i].ldc = ldc; pb.d[i].dbase = dbase; pb.d[i].base = blk;
    gb.n = pb.n = i + 1;
    wg += mt * nt * CSPLIT;
    blk += mt * nt * 16;
    sp += (size_t)mt * nt * 16384;
  }
};

extern "C" void kernel_launch(void* const* d_in, const int* in_sizes, int n_in,
                              void* d_out, int out_size, void* d_ws, size_t ws_size,
                              hipStream_t stream)
{
  const float* inp = (const float*)d_in[0];
  const float* Aw  = (const float*)d_in[1];
  const float* Bw  = (const float*)d_in[2];
  const float* Cw  = (const float*)d_in[3];
  const float* Dw  = (const float*)d_in[4];
  float* out = (float*)d_out;
  (void)in_sizes; (void)n_in; (void)out_size; (void)ws_size;

  char* ws = (char*)d_ws;
  size_t off = 0;
  auto carve = [&](size_t bytes) { char* p = ws + off; off += (bytes + 255) & ~(size_t)255; return p; };
  const size_t M1 = (size_t)1024 * 1024;
  bf16* Ahr = (bf16*)carve(M1 * 2); bf16* Alr = (bf16*)carve(M1 * 2);
  bf16* Ahc = (bf16*)carve(M1 * 2); bf16* Alc = (bf16*)carve(M1 * 2);
  bf16* QAhr = (bf16*)carve(M1 * 2); bf16* QAlr = (bf16*)carve(M1 * 2);
  bf16* QAhc = (bf16*)carve(M1 * 2); bf16* QAlc = (bf16*)carve(M1 * 2);
  bf16* QBhr = (bf16*)carve(M1 * 2); bf16* QBlr = (bf16*)carve(M1 * 2);
  bf16* QBhc = (bf16*)carve(M1 * 2); bf16* QBlc = (bf16*)carve(M1 * 2);
  bf16* Ghr = (bf16*)carve((size_t)2048 * 1024 * 2);   // G_j = C A^j, j=0..15
  bf16* Glr = (bf16*)carve((size_t)2048 * 1024 * 2);
  bf16* Rth = (bf16*)carve((size_t)896 * 1024 * 2);    // R_m^T rows, m=0..6
  bf16* Rtl = (bf16*)carve((size_t)896 * 1024 * 2);
  bf16* Kbt = (bf16*)carve((size_t)128 * KTOT * 2);
  bf16* Ubf = (bf16*)carve((size_t)(LTRUNC + NSTEPS) * 128 * 2);
  float* SLAB = (float*)carve((size_t)2 * 1024 * 1024 * 4);   // 8 MB level slab

  auto runlvl = [&](Builder& b) {
    hipMemsetAsync(b.slab0, 0, (size_t)((char*)b.sp - (char*)b.slab0), stream);
    chain_gemm<<<b.wg, 256, 0, stream>>>(b.gb);
    pack<<<b.blk, 256, 0, stream>>>(b.pb);
  };

  // ---- input transpose (pad rows zeroed) ----
  hipMemsetAsync(Ubf, 0, (size_t)LTRUNC * 128 * 2, stream);
  ubuild<<<dim3(NSTEPS / 64, 2), 256, 0, stream>>>(inp, Ubf);

  // ---- splits of the raw weights ----
  split_rm<<<1024, 256, 0, stream>>>(Aw, Ahr, Alr);                     // A row-major
  split_cm<<<dim3(16, 16), 256, 0, stream>>>(Aw, Ahc, Alc, 1024, 1024); // A col-major
  split_rm<<<128, 256, 0, stream>>>(Cw, Ghr, Glr);                      // G_0 = C
  split_cm<<<dim3(2, 16), 256, 0, stream>>>(Bw, Rth, Rtl, 1024, 128);   // R_0^T = B^T
  dinit<<<64, 256, 0, stream>>>(Dw, Kbt);                               // K_0 = D

  // ---- 8-level chain: squarings + G/R doubling + K bank, batched per level ----
  { Builder b(SLAB);                                                     // L1: A^2, G1
    b.add(Ahr, Alr, Ahc, Alc, 8, 8, QAhr, QAlr, 1024, QAhc, QAlc, 1024, nullptr, 0);
    b.add(Ghr, Glr, Ahc, Alc, 1, 8, Ghr + (size_t)128 * 1024, Glr + (size_t)128 * 1024, 1024,
          nullptr, nullptr, 0, nullptr, 0);
    runlvl(b); }
  { Builder b(SLAB);                                                     // L2: A^4, G2-3
    b.add(QAhr, QAlr, QAhc, QAlc, 8, 8, QBhr, QBlr, 1024, QBhc, QBlc, 1024, nullptr, 0);
    b.add(Ghr, Glr, QAhc, QAlc, 2, 8, Ghr + (size_t)256 * 1024, Glr + (size_t)256 * 1024, 1024,
          nullptr, nullptr, 0, nullptr, 0);
    runlvl(b); }
  { Builder b(SLAB);                                                     // L3: A^8, G4-7
    b.add(QBhr, QBlr, QBhc, QBlc, 8, 8, QAhr, QAlr, 1024, QAhc, QAlc, 1024, nullptr, 0);
    b.add(Ghr, Glr, QBhc, QBlc, 4, 8, Ghr + (size_t)512 * 1024, Glr + (size_t)512 * 1024, 1024,
          nullptr, nullptr, 0, nullptr, 0);
    runlvl(b); }
  { Builder b(SLAB);                                                     // L4: A^16, G8-15
    b.add(QAhr, QAlr, QAhc, QAlc, 8, 8, QBhr, QBlr, 1024, QBhc, QBlc, 1024, nullptr, 0);
    b.add(Ghr, Glr, QAhc, QAlc, 8, 8, Ghr + M1, Glr + M1, 1024,
          nullptr, nullptr, 0, nullptr, 0);
    runlvl(b); }
  { Builder b(SLAB);                                                     // L5: A^32, R1
    b.add(QBhr, QBlr, QBhc, QBlc, 8, 8, QAhr, QAlr, 1024, QAhc, QAlc, 1024, nullptr, 0);
    b.add(QBhr, QBlr, Rth, Rtl, 8, 1, nullptr, nullptr, 0,
          Rth + (size_t)128 * 1024, Rtl + (size_t)128 * 1024, 1024, nullptr, 0);
    runlvl(b); }
  { Builder b(SLAB);                                                     // L6: A^64, R2-3
    b.add(QAhr, QAlr, QAhc, QAlc, 8, 8, QBhr, QBlr, 1024, QBhc, QBlc, 1024, nullptr, 0);
    b.add(QAhr, QAlr, Rth, Rtl, 8, 2, nullptr, nullptr, 0,
          Rth + (size_t)256 * 1024, Rtl + (size_t)256 * 1024, 1024, nullptr, 0);
    runlvl(b); }
  { Builder b(SLAB);                                                     // L7: R4-6, K m=0..3
    b.add(QBhr, QBlr, Rth, Rtl, 8, 3, nullptr, nullptr, 0,
          Rth + (size_t)384 * 1024, Rtl + (size_t)384 * 1024, 1024, nullptr, 0);
    for (int m = 0; m < 4; ++m)
      b.add(Ghr, Glr, Rth + (size_t)m * 128 * 1024, Rtl + (size_t)m * 128 * 1024, 16, 1,
            nullptr, nullptr, 0, nullptr, nullptr, 0, Kbt, 1 + 16 * m);
    runlvl(b); }
  { Builder b(SLAB);                                                     // L8: K m=4..6
    for (int m = 4; m < 7; ++m)
      b.add(Ghr, Glr, Rth + (size_t)m * 128 * 1024, Rtl + (size_t)m * 128 * 1024, 16, 1,
            nullptr, nullptr, 0, nullptr, nullptr, 0, Kbt, 1 + 16 * m);
    runlvl(b); }

  // ---- main conv ----
  hipMemsetAsync(out, 0, (size_t)NSTEPS * 128 * 4, stream);
  conv_mfma<<<dim3(NSTEPS / 128, SPLITK), 256, 0, stream>>>(Ubf, Kbt, out);
}